// Round 9
// baseline (254.746 us; speedup 1.0000x reference)
//
#include <hip/hip_runtime.h>
#include <hip/hip_bf16.h>

#define BB 4
#define CC 256
#define NN 4096
#define BBNN (BB * NN)
#define NGROUPS 32
#define CPG 8
#define EPSG 1e-6f
#define QKSCL 0.30028063f             // sqrt(C^-0.5 * log2(e)) folded into q and k
#define KSPLIT 4
#define JITERS (NN / KSPLIT / 64)     // 16
#define KSTRIDE 272                   // 17 granules: padded K row (bank-spread)
#define VSTRIDE 80                    // 5 granules: padded V row -> 2-way banks
#define VBYTES (256 * VSTRIDE)        // 20480 B per V buffer
#define DEFER_THR 8.0f                // defer-max: P bounded by 2^8=256 < fp8 max 448

// sigma(c): channel permutation applied to BOTH q8 and k8 columns so that a
// lane's (q4, kc) and (q4, kc+1) 8B fragments are 16B-contiguous ->
// QK LDS reads become ds_read_b128 (16 reads/wave-iter instead of 32) and
// the read pattern (bank group = (m + q4 + 4*c16) mod 8) is conflict-free.
// Dot products over c are invariant under a shared permutation; V untouched.
#define SIGMA(c) (((c) & 0xC0) | (((c) & 0x18) << 1) | (((c) & 0x20) >> 2) | ((c) & 7))

typedef __bf16 bf16x8 __attribute__((ext_vector_type(8)));
typedef float  f32x4  __attribute__((ext_vector_type(4)));

typedef __attribute__((address_space(1))) const void g_void;
typedef __attribute__((address_space(3))) void l_void;

__device__ __forceinline__ unsigned short f2bf(float f) {
  unsigned u = __builtin_bit_cast(unsigned, f);
  u += 0x7fffu + ((u >> 16) & 1u);
  return (unsigned short)(u >> 16);
}
__device__ __forceinline__ float bf2f(unsigned short s) {
  return __builtin_bit_cast(float, (unsigned)s << 16);
}

__device__ __forceinline__ f32x4 mfma16(bf16x8 a, bf16x8 b, f32x4 c) {
  return __builtin_amdgcn_mfma_f32_16x16x32_bf16(a, b, c, 0, 0, 0);
}
__device__ __forceinline__ f32x4 mfma8(long a, long b, f32x4 c) {
  return __builtin_amdgcn_mfma_f32_16x16x32_fp8_fp8(a, b, c, 0, 0, 0);
}

__device__ __forceinline__ bf16x8 ldfrag(const unsigned short* p) {
  return __builtin_bit_cast(bf16x8, *(const uint4*)p);
}

// ---- fused: weights fp32->bf16 (blocks 0..255) + GroupNorm stats (256..511) ----
__global__ __launch_bounds__(256) void pre(const float* __restrict__ wq,
    const float* __restrict__ wk, const float* __restrict__ wv,
    const float* __restrict__ wo, const float* __restrict__ x,
    unsigned short* __restrict__ wbf, float* __restrict__ part) {
  if (blockIdx.x < 256) {
    int mat = blockIdx.x >> 6, blk = blockIdx.x & 63;
    const float* s = mat == 0 ? wq : mat == 1 ? wk : mat == 2 ? wv : wo;
    int i = (blk * 256 + threadIdx.x) * 4;
    float4 v = *(const float4*)&s[i];
    unsigned short* d = wbf + (size_t)mat * CC * CC + i;
    d[0] = f2bf(v.x); d[1] = f2bf(v.y); d[2] = f2bf(v.z); d[3] = f2bf(v.w);
    return;
  }
  int bx = blockIdx.x - 256;
  int pair = bx >> 1, h = bx & 1;
  const float* xp = x + (size_t)pair * (CPG * NN) + (size_t)h * (CPG * NN / 2);
  float s = 0.f, s2 = 0.f;
  for (int i = threadIdx.x; i < CPG * NN / 8; i += 256) {
    float4 v = ((const float4*)xp)[i];
    s += v.x + v.y + v.z + v.w;
    s2 += v.x * v.x + v.y * v.y + v.z * v.z + v.w * v.w;
  }
  for (int o = 32; o; o >>= 1) { s += __shfl_down(s, o); s2 += __shfl_down(s2, o); }
  __shared__ float rs[4], rs2[4];
  int wid = threadIdx.x >> 6, lane = threadIdx.x & 63;
  if (lane == 0) { rs[wid] = s; rs2[wid] = s2; }
  __syncthreads();
  if (threadIdx.x == 0) {
    part[bx * 2 + 0] = rs[0] + rs[1] + rs[2] + rs[3];
    part[bx * 2 + 1] = rs2[0] + rs2[1] + rs2[2] + rs2[3];
  }
}

// ---- fused GroupNorm + QKV, all three projections per block ----
// grid 256 = 4 b x 64 ntiles (low3 XCD-pins), 512 threads (8 waves).
// q8/k8 columns are written at SIGMA(o) (see above); v8 unpermuted.
__global__ __launch_bounds__(512) void gqkv(const float* __restrict__ x,
    const float* __restrict__ gw, const float* __restrict__ gb,
    const float* __restrict__ part, const unsigned short* __restrict__ wbf,
    const float* __restrict__ bq, const float* __restrict__ bk,
    const float* __restrict__ bv,
    unsigned char* __restrict__ q8, unsigned char* __restrict__ k8,
    unsigned char* __restrict__ v8) {
  const int low = blockIdx.x & 7;
  const int b = low & 3, shalf = low >> 2;
  const int u = blockIdx.x >> 3;        // 0..31
  const int sidx = (u >> 4) * 2 + shalf;
  const int nt = sidx * 16 + (u & 15);
  const int n0 = nt * 64;
  __shared__ unsigned short Xs[64][CC + 8];
  int tid = threadIdx.x;
  const float* xb = x + (size_t)b * CC * NN;
  {                                      // 512 items of (8c x 4n), one each
    int item = tid;
    int g = item >> 4, nc = item & 15;
    int pair = b * NGROUPS + g;
    float s = part[pair * 4 + 0] + part[pair * 4 + 2];
    float s2 = part[pair * 4 + 1] + part[pair * 4 + 3];
    float mean = s / (CPG * NN);
    float inv = rsqrtf(s2 / (CPG * NN) - mean * mean + EPSG);
    unsigned short row[4][8];
#pragma unroll
    for (int cc = 0; cc < 8; ++cc) {
      int c = g * 8 + cc;
      float wv = gw[c];
      float scv = inv * wv;
      float biv = gb[c] - mean * scv;
      float4 v = *(const float4*)&xb[(size_t)c * NN + n0 + nc * 4];
      row[0][cc] = f2bf(v.x * scv + biv);
      row[1][cc] = f2bf(v.y * scv + biv);
      row[2][cc] = f2bf(v.z * scv + biv);
      row[3][cc] = f2bf(v.w * scv + biv);
    }
#pragma unroll
    for (int r = 0; r < 4; ++r)
      *(uint4*)&Xs[nc * 4 + r][g * 8] = *(const uint4*)&row[r][0];
  }
  __syncthreads();
  int w = tid >> 6, lane = tid & 63;
  int m = lane & 15, q4 = lane >> 4;
  int mode = w >> 2, wsub = w & 3;       // waves 0-3: Q rows; waves 4-7: K rows
  {
    bf16x8 xa[8];
#pragma unroll
    for (int k = 0; k < 8; ++k)
      xa[k] = ldfrag(&Xs[wsub * 16 + m][k * 32 + q4 * 8]);
    const unsigned short* W = wbf + (size_t)mode * CC * CC;
    const float* bias = mode ? bk : bq;
    unsigned char* dst = mode ? k8 : q8;
    for (int ot = 0; ot < 16; ++ot) {
      f32x4 acc = {0.f, 0.f, 0.f, 0.f};
#pragma unroll
      for (int k = 0; k < 8; ++k) {
        bf16x8 bf = ldfrag(&W[(size_t)(ot * 16 + m) * CC + k * 32 + q4 * 8]);
        acc = mfma16(xa[k], bf, acc);
      }
      int o = ot * 16 + m;
      int so = SIGMA(o);                 // permuted column for q8/k8
      float bia = bias[o];
      unsigned pk01 = __builtin_amdgcn_cvt_pk_fp8_f32(
          (acc[0] + bia) * QKSCL, (acc[1] + bia) * QKSCL, 0u, false);
      unsigned pk23 = __builtin_amdgcn_cvt_pk_fp8_f32(
          (acc[2] + bia) * QKSCL, (acc[3] + bia) * QKSCL, 0u, false);
      size_t base = ((size_t)b * NN + n0 + wsub * 16 + q4 * 4) * CC + so;
      dst[base]          = (unsigned char)(pk01 & 0xff);
      dst[base + CC]     = (unsigned char)((pk01 >> 8) & 0xff);
      dst[base + 2 * CC] = (unsigned char)(pk23 & 0xff);
      dst[base + 3 * CC] = (unsigned char)((pk23 >> 8) & 0xff);
    }
  }
  // ---- V phase: 8 waves split 4 o-groups x 2 nt4-halves (unpermuted) ----
  {
    const unsigned short* Wv = wbf + 2 * CC * CC;
    int nthalf = w >> 2;                 // 0: nt4 {0,1}; 1: nt4 {2,3}
    for (int ot = 0; ot < 4; ++ot) {
      int o0 = (w & 3) * 64 + ot * 16;
      bf16x8 af[8];
#pragma unroll
      for (int k = 0; k < 8; ++k)
        af[k] = ldfrag(&Wv[(size_t)(o0 + m) * CC + k * 32 + q4 * 8]);
#pragma unroll
      for (int hh = 0; hh < 2; ++hh) {
        int nt4 = nthalf * 2 + hh;
        f32x4 acc = {0.f, 0.f, 0.f, 0.f};
#pragma unroll
        for (int k = 0; k < 8; ++k) {
          bf16x8 bfr = ldfrag(&Xs[nt4 * 16 + m][k * 32 + q4 * 8]);
          acc = mfma16(af[k], bfr, acc);
        }
        // K-dim permutation within the 64-block: j -> j''
        int j = nt4 * 16 + m;
        int jp = (j & 0x23) | ((j & 0x0C) << 1) | ((j & 0x10) >> 2);
        int n = n0 + jp;
        int o = o0 + q4 * 4;
        unsigned pk01 = __builtin_amdgcn_cvt_pk_fp8_f32(acc[0] + bv[o], acc[1] + bv[o + 1], 0u, false);
        unsigned pk23 = __builtin_amdgcn_cvt_pk_fp8_f32(acc[2] + bv[o + 2], acc[3] + bv[o + 3], 0u, false);
        size_t base = ((size_t)b * CC + o) * NN + n;
        v8[base]          = (unsigned char)(pk01 & 0xff);
        v8[base + NN]     = (unsigned char)((pk01 >> 8) & 0xff);
        v8[base + 2 * NN] = (unsigned char)(pk23 & 0xff);
        v8[base + 3 * NN] = (unsigned char)((pk23 >> 8) & 0xff);
      }
    }
  }
}

// DMA one 64-j fp8 K tile into PADDED LDS (row stride 272B = 17 granules).
// Layout-agnostic byte copy (k8 rows are already sigma-permuted).
// 256-thread version: 1088 granules = 4x256 + 64-thread tail (wave 0).
__device__ __forceinline__ void stageK8(const unsigned char* __restrict__ kp,
    int j0, unsigned char* Kb, int tid) {
#pragma unroll
  for (int t = 0; t < 4; ++t) {
    int item = t * 256 + tid;
    int row = item / 17, g = item % 17;
    int gs = (g == 16) ? 0 : g;
    const unsigned char* gp = kp + (size_t)(j0 + row) * CC + gs * 16;
    __builtin_amdgcn_global_load_lds((g_void*)gp, (l_void*)(Kb + item * 16), 16, 0, 0);
  }
  if (tid < 64) {                       // wave-0-uniform tail: items 1024..1087
    int item = 1024 + tid;
    int row = item / 17, g = item % 17;
    int gs = (g == 16) ? 0 : g;
    const unsigned char* gp = kp + (size_t)(j0 + row) * CC + gs * 16;
    __builtin_amdgcn_global_load_lds((g_void*)gp, (l_void*)(Kb + item * 16), 16, 0, 0);
  }
}
// DMA one 64-j fp8 V tile into PADDED LDS (row stride 80B = 5 granules,
// identity granule placement; pad granule duplicates granule 0).
// Row stride 80B makes the PV b64 read pattern 2-way (floor) instead of
// 4-way banked: bank-pair = (10m + 2g + q4l) mod 16 spreads rows.
// 1280 granules = 5 x 256 threads.
__device__ __forceinline__ void stageV8(const unsigned char* __restrict__ vp,
    int j0, unsigned char* Vb, int tid) {
#pragma unroll
  for (int t = 0; t < 5; ++t) {
    int item = t * 256 + tid;           // 0..1279
    int row = item / 5, g5 = item % 5;
    int gs = (g5 == 4) ? 0 : g5;
    const unsigned char* g = vp + (size_t)row * NN + j0 + gs * 16;
    __builtin_amdgcn_global_load_lds((g_void*)g, (l_void*)(Vb + item * 16), 16, 0, 0);
  }
}

// ---- flash attention, S^T form: grid 512 = 16 (s,b) x 32 itiles, 256 thr ----
// 4 waves/block; each wave owns 32 Q-rows (subtiles A,B) sharing every
// K/V-fragment LDS read; sigma layout -> QK = 16 conflict-free ds_read_b128.
// V rows padded to 80B, identity granules -> PV b64 reads at the 2-way floor
// (was 4-way: 4.1 kcyc/CU-iter of SQ_LDS_BANK_CONFLICT, 35% of iter period).
// voff loses its m-XOR: identity-store o identity-read == old XOR o XOR.
// CROSS-ITERATION PV PIPELINE: iteration jt issues one merged MFMA burst
// {QK(jt), PV(jt-1)}, then barrier B, stage(jt+1), softmax(jt)->pd(jt).
// K single buffer; V double buffer. LDS 17408 + 2*20480 = 58368B.
__global__ __launch_bounds__(256, 2) void attn(const unsigned char* __restrict__ q8,
    const unsigned char* __restrict__ k8, const unsigned char* __restrict__ v8,
    unsigned short* __restrict__ accP, float* __restrict__ mlP) {
  const int grp = blockIdx.x & 15;
  const int s = grp >> 2, b = grp & 3;
  const int it = blockIdx.x >> 4;       // 0..31
  const int i0 = it * 128;
  __shared__ __align__(16) unsigned char pool[17408 + 2 * VBYTES];
  unsigned char* Kd  = pool;                    // 64*272 = 17408 B (single)
  unsigned char* Vd0 = pool + 17408;            // 20480 B
  unsigned char* Vd1 = pool + 17408 + VBYTES;   // 20480 B
  int tid = threadIdx.x, w = tid >> 6, lane = tid & 63;
  int m = lane & 15, q4 = lane >> 4;
  const unsigned char* kp = k8 + (size_t)b * NN * CC;
  const unsigned char* vp = v8 + (size_t)b * CC * NN;
  const int iA0 = i0 + w * 32;          // subtile A rows; B = A + 16
  long qaA[8], qaB[8];
#pragma unroll
  for (int t = 0; t < 4; ++t) {         // sigma layout: 16B-contiguous kc pairs
    uint4 va = *(const uint4*)&q8[((size_t)b * NN + iA0 + m) * CC + t * 64 + q4 * 16];
    uint4 vb = *(const uint4*)&q8[((size_t)b * NN + iA0 + 16 + m) * CC + t * 64 + q4 * 16];
    uint2 alo = {va.x, va.y}, ahi = {va.z, va.w};
    uint2 blo = {vb.x, vb.y}, bhi = {vb.z, vb.w};
    qaA[2 * t]     = __builtin_bit_cast(long, alo);
    qaA[2 * t + 1] = __builtin_bit_cast(long, ahi);
    qaB[2 * t]     = __builtin_bit_cast(long, blo);
    qaB[2 * t + 1] = __builtin_bit_cast(long, bhi);
  }
  f32x4 accA[16], accB[16];
#pragma unroll
  for (int i = 0; i < 16; ++i) {
    accA[i] = (f32x4){0.f, 0.f, 0.f, 0.f};
    accB[i] = (f32x4){0.f, 0.f, 0.f, 0.f};
  }
  float mrowA = -1e30f, lrowA = 0.f, mrowB = -1e30f, lrowB = 0.f;
  const int jbase = s * (NN / KSPLIT);
  stageK8(kp, jbase, Kd, tid);
  stageV8(vp, jbase, Vd0, tid);
  const unsigned char* Kbase = Kd + m * KSTRIDE + q4 * 16;  // b128 reads: +imm
  const int voff  = q4 * 8;             // PV p=0 (identity granules)
  const int voff1 = 32 + q4 * 8;        // PV p=1
  unsigned pdA[4] = {0, 0, 0, 0}, pdB[4] = {0, 0, 0, 0};    // carried pd(jt-1)
  for (int jt = 0; jt < JITERS; ++jt) {
    __syncthreads();         // barrier A: stage(jt) landed (this wave's own
                             // vmcnt(0) drain + all waves' barrier)
    const unsigned char* Vprev = (jt & 1) ? Vd0 : Vd1;  // V(jt-1) buffer
    f32x4 svA[4], svB[4];
    __builtin_amdgcn_s_setprio(1);
    // ---- merged MFMA burst: QK(jt) + PV(jt-1), fully independent ----
#pragma unroll
    for (int jt4 = 0; jt4 < 4; ++jt4) {
      f32x4 aA = {0.f, 0.f, 0.f, 0.f};
      f32x4 aB = {0.f, 0.f, 0.f, 0.f};
#pragma unroll
      for (int c16 = 0; c16 < 4; ++c16) {
        uint4 kq = *(const uint4*)&Kbase[jt4 * 16 * KSTRIDE + c16 * 64];
        uint2 l2 = {kq.x, kq.y}, h2 = {kq.z, kq.w};
        long klo = __builtin_bit_cast(long, l2);
        long khi = __builtin_bit_cast(long, h2);
        aA = mfma8(klo, qaA[2 * c16], aA);
        aB = mfma8(klo, qaB[2 * c16], aB);
        aA = mfma8(khi, qaA[2 * c16 + 1], aA);
        aB = mfma8(khi, qaB[2 * c16 + 1], aB);
      }
      svA[jt4] = aA;
      svB[jt4] = aB;
    }
    if (jt > 0) {            // PV(jt-1) with carried pd, V(jt-1) buffer
#pragma unroll
      for (int p = 0; p < 2; ++p) {
        uint2 puA = {pdA[2 * p], pdA[2 * p + 1]};
        uint2 puB = {pdB[2 * p], pdB[2 * p + 1]};
        long pTA = __builtin_bit_cast(long, puA);
        long pTB = __builtin_bit_cast(long, puB);
        int vo = p ? voff1 : voff;
#pragma unroll
        for (int ct = 0; ct < 16; ++ct) {
          long vf = *(const long*)&Vprev[(ct * 16 + m) * VSTRIDE + vo];
          accA[ct] = mfma8(vf, pTA, accA[ct]);
          accB[ct] = mfma8(vf, pTB, accB[ct]);
        }
      }
    }
    __builtin_amdgcn_s_setprio(0);
    __syncthreads();         // barrier B: all waves done reading Kd & V(jt-1)
                             // (no vmem outstanding -> cheap drain)
    if (jt + 1 < JITERS) {   // restage K (single buf) + V[(jt+1)&1]
      stageK8(kp, jbase + (jt + 1) * 64, Kd, tid);
      stageV8(vp, jbase + (jt + 1) * 64, ((jt + 1) & 1) ? Vd1 : Vd0, tid);
    }
    // ---- softmax(jt) -> pd(jt); consumed next iteration ----
    float mxA = -1e30f, mxB = -1e30f;
#pragma unroll
    for (int jt4 = 0; jt4 < 4; ++jt4) {
      mxA = fmaxf(mxA, fmaxf(fmaxf(svA[jt4][0], svA[jt4][1]), fmaxf(svA[jt4][2], svA[jt4][3])));
      mxB = fmaxf(mxB, fmaxf(fmaxf(svB[jt4][0], svB[jt4][1]), fmaxf(svB[jt4][2], svB[jt4][3])));
    }
    mxA = fmaxf(mxA, __shfl_xor(mxA, 16));
    mxA = fmaxf(mxA, __shfl_xor(mxA, 32));
    mxB = fmaxf(mxB, __shfl_xor(mxB, 16));
    mxB = fmaxf(mxB, __shfl_xor(mxB, 32));
    if (__any(mxA - mrowA > DEFER_THR)) {   // rare: update m, rescale A
      float mnewA = fmaxf(mrowA, mxA);
      float alphaA = exp2f(mrowA - mnewA);
      mrowA = mnewA;
      lrowA *= alphaA;
#pragma unroll
      for (int ct = 0; ct < 16; ++ct) accA[ct] *= alphaA;
    }
    if (__any(mxB - mrowB > DEFER_THR)) {   // rare: update m, rescale B
      float mnewB = fmaxf(mrowB, mxB);
      float alphaB = exp2f(mrowB - mnewB);
      mrowB = mnewB;
      lrowB *= alphaB;
#pragma unroll
      for (int ct = 0; ct < 16; ++ct) accB[ct] *= alphaB;
    }
    float rsumA = 0.f, rsumB = 0.f;
#pragma unroll
    for (int jt4 = 0; jt4 < 4; ++jt4) {
      float e0 = exp2f(svA[jt4][0] - mrowA);
      float e1 = exp2f(svA[jt4][1] - mrowA);
      float e2 = exp2f(svA[jt4][2] - mrowA);
      float e3 = exp2f(svA[jt4][3] - mrowA);
      rsumA += (e0 + e1) + (e2 + e3);
      unsigned d = __builtin_amdgcn_cvt_pk_fp8_f32(e0, e1, 0u, false);
      pdA[jt4] = __builtin_amdgcn_cvt_pk_fp8_f32(e2, e3, d, true);
      float f0 = exp2f(svB[jt4][0] - mrowB);
      float f1 = exp2f(svB[jt4][1] - mrowB);
      float f2 = exp2f(svB[jt4][2] - mrowB);
      float f3 = exp2f(svB[jt4][3] - mrowB);
      rsumB += (f0 + f1) + (f2 + f3);
      unsigned e = __builtin_amdgcn_cvt_pk_fp8_f32(f0, f1, 0u, false);
      pdB[jt4] = __builtin_amdgcn_cvt_pk_fp8_f32(f2, f3, e, true);
    }
    rsumA += __shfl_xor(rsumA, 16);
    rsumA += __shfl_xor(rsumA, 32);
    rsumB += __shfl_xor(rsumB, 16);
    rsumB += __shfl_xor(rsumB, 32);
    lrowA += rsumA;
    lrowB += rsumB;
  }
  // ---- epilogue PV(JITERS-1): V(15) in buf[15&1]=Vd1, untouched since ----
  {
    const unsigned char* Vlast = ((JITERS - 1) & 1) ? Vd1 : Vd0;
#pragma unroll
    for (int p = 0; p < 2; ++p) {
      uint2 puA = {pdA[2 * p], pdA[2 * p + 1]};
      uint2 puB = {pdB[2 * p], pdB[2 * p + 1]};
      long pTA = __builtin_bit_cast(long, puA);
      long pTB = __builtin_bit_cast(long, puB);
      int vo = p ? voff1 : voff;
#pragma unroll
      for (int ct = 0; ct < 16; ++ct) {
        long vf = *(const long*)&Vlast[(ct * 16 + m) * VSTRIDE + vo];
        accA[ct] = mfma8(vf, pTA, accA[ct]);
        accB[ct] = mfma8(vf, pTB, accB[ct]);
      }
    }
  }
  // epilogue: per-lane (i = m) stats for both subtiles; O^T -> LDS transpose
  // -> coalesced store. 128 rows in two 64-row passes (waves 0-1, then 2-3).
  size_t rqA = (size_t)(s * BB + b) * NN + iA0 + m;
  if (q4 == 0) {
    mlP[rqA * 2 + 0] = mrowA;
    mlP[rqA * 2 + 1] = lrowA;
    mlP[(rqA + 16) * 2 + 0] = mrowB;
    mlP[(rqA + 16) * 2 + 1] = lrowB;
  }
  __syncthreads();                      // all PV reads done before pool reuse
  unsigned short* tp = (unsigned short*)pool;   // 64 rows x 260 shorts = 33.3KB
#pragma unroll
  for (int half = 0; half < 2; ++half) {
    if ((w >> 1) == half) {
      int rbase = (w & 1) * 32;
#pragma unroll
      for (int ct = 0; ct < 16; ++ct) {
        unsigned loA = f2bf(accA[ct][0]) | ((unsigned)f2bf(accA[ct][1]) << 16);
        unsigned hiA = f2bf(accA[ct][2]) | ((unsigned)f2bf(accA[ct][3]) << 16);
        uint2 pkA = {loA, hiA};
        *(uint2*)&tp[(rbase + m) * 260 + ct * 16 + q4 * 4] = pkA;
        unsigned loB = f2bf(accB[ct][0]) | ((unsigned)f2bf(accB[ct][1]) << 16);
        unsigned hiB = f2bf(accB[ct][2]) | ((unsigned)f2bf(accB[ct][3]) << 16);
        uint2 pkB = {loB, hiB};
        *(uint2*)&tp[(rbase + 16 + m) * 260 + ct * 16 + q4 * 4] = pkB;
      }
    }
    __syncthreads();
#pragma unroll
    for (int u = 0; u < 8; ++u) {
      int id = u * 256 + tid;           // 2048 items = 64 rows x 32 chunks
      int row = id >> 5, ck = id & 31;
      uint4 v = *(const uint4*)&tp[row * 260 + ck * 8];
      *(uint4*)&accP[((size_t)(s * BB + b) * NN + i0 + half * 64 + row) * CC + ck * 8] = v;
    }
    __syncthreads();
  }
}

// ---- output projection + combine partials + bias + residual; grid 512 ----
__global__ __launch_bounds__(256) void proj(const unsigned short* __restrict__ accP,
    const float* __restrict__ mlP, const unsigned short* __restrict__ Wo,
    const float* __restrict__ bo, const float* __restrict__ x,
    float* __restrict__ out) {
  const int b = blockIdx.x >> 7, nt = blockIdx.x & 127;
  const int n0 = nt * 32;
  __shared__ unsigned short As[32][CC + 8];
  __shared__ float wr[KSPLIT][36];
  int tid = threadIdx.x;
  if (tid < 32) {
    int n = n0 + tid;
    float mv[KSPLIT], lv[KSPLIT], M = -1e30f;
#pragma unroll
    for (int s = 0; s < KSPLIT; ++s) {
      size_t rq = (size_t)(s * BB + b) * NN + n;
      mv[s] = mlP[rq * 2];
      lv[s] = mlP[rq * 2 + 1];
      M = fmaxf(M, mv[s]);
    }
    float ws[KSPLIT], d = 0.f;
#pragma unroll
    for (int s = 0; s < KSPLIT; ++s) {
      ws[s] = exp2f(mv[s] - M);
      d += lv[s] * ws[s];
    }
    float inv = 1.f / d;
#pragma unroll
    for (int s = 0; s < KSPLIT; ++s) wr[s][tid] = ws[s] * inv;
  }
  __syncthreads();
#pragma unroll
  for (int i = 0; i < 4; ++i) {
    int id = tid + 256 * i;
    int r = id >> 5, ck = id & 31;
    int n = n0 + r;
    float f[8] = {0.f, 0.f, 0.f, 0.f, 0.f, 0.f, 0.f, 0.f};
#pragma unroll
    for (int s = 0; s < KSPLIT; ++s) {
      uint4 a = *(const uint4*)&accP[((size_t)(s * BB + b) * NN + n) * CC + ck * 8];
      const unsigned* p = (const unsigned*)&a;
      float wgt = wr[s][r];
#pragma unroll
      for (int k = 0; k < 4; ++k) {
        f[k * 2 + 0] += bf2f((unsigned short)(p[k] & 0xffff)) * wgt;
        f[k * 2 + 1] += bf2f((unsigned short)(p[k] >> 16)) * wgt;
      }
    }
    unsigned short ov[8];
#pragma unroll
    for (int k = 0; k < 8; ++k) ov[k] = f2bf(f[k]);
    *(uint4*)&As[r][ck * 8] = *(const uint4*)&ov[0];
  }
  __syncthreads();
  int w = tid >> 6, lane = tid & 63, m = lane & 15, q4 = lane >> 4;
  for (int ot = 0; ot < 4; ++ot) {
    int o0 = w * 64 + ot * 16;
    bf16x8 af[8];
#pragma unroll
    for (int k = 0; k < 8; ++k)
      af[k] = ldfrag(&Wo[(size_t)(o0 + m) * CC + k * 32 + q4 * 8]);
#pragma unroll
    for (int nt4 = 0; nt4 < 2; ++nt4) {
      f32x4 a = {0.f, 0.f, 0.f, 0.f};
#pragma unroll
      for (int k = 0; k < 8; ++k) {
        bf16x8 bf = ldfrag(&As[nt4 * 16 + m][k * 32 + q4 * 8]);
        a = mfma16(af[k], bf, a);
      }
      int n = n0 + nt4 * 16 + m;
#pragma unroll
      for (int r = 0; r < 4; ++r) {
        int o = o0 + q4 * 4 + r;
        size_t idx = ((size_t)b * CC + o) * NN + n;
        out[idx] = x[idx] + bo[o] + a[r];
      }
    }
  }
}

extern "C" void kernel_launch(void* const* d_in, const int* in_sizes, int n_in,
                              void* d_out, int out_size, void* d_ws, size_t ws_size,
                              hipStream_t stream) {
  const float* x  = (const float*)d_in[0];
  const float* gw = (const float*)d_in[1];
  const float* gb = (const float*)d_in[2];
  const float* wq = (const float*)d_in[3];
  const float* bq = (const float*)d_in[4];
  const float* wk = (const float*)d_in[5];
  const float* bk = (const float*)d_in[6];
  const float* wv = (const float*)d_in[7];
  const float* bv = (const float*)d_in[8];
  const float* wo = (const float*)d_in[9];
  const float* bo = (const float*)d_in[10];

  const size_t M4 = (size_t)BB * NN * CC;
  unsigned short* wbf = (unsigned short*)d_ws;          // 4*65536 bf16
  unsigned short* accPb = wbf + 4 * CC * CC;            // KSPLIT*M4 bf16
  float* mlP  = (float*)(accPb + (size_t)KSPLIT * M4);  // KSPLIT*BBNN*2 f32
  float* part = mlP + (size_t)KSPLIT * BBNN * 2;        // 512 f32
  unsigned char* q8 = (unsigned char*)(part + 512);
  unsigned char* k8 = q8 + M4;
  unsigned char* v8 = k8 + M4;

  pre<<<512, 256, 0, stream>>>(wq, wk, wv, wo, x, wbf, part);
  gqkv<<<256, 512, 0, stream>>>(x, gw, gb, part, wbf, bq, bk, bv, q8, k8, v8);
  attn<<<KSPLIT * BB * 32, 256, 0, stream>>>(q8, k8, v8, accPb, mlP);
  proj<<<512, 256, 0, stream>>>(accPb, mlP, wbf + 3 * CC * CC, bo, x, (float*)d_out);
}

// Round 10
// 204.395 us; speedup vs baseline: 1.2463x; 1.2463x over previous
//
#include <hip/hip_runtime.h>
#include <hip/hip_bf16.h>

#define BB 4
#define CC 256
#define NN 4096
#define BBNN (BB * NN)
#define NGROUPS 32
#define CPG 8
#define EPSG 1e-6f
#define QKSCL 0.30028063f             // sqrt(C^-0.5 * log2(e)) folded into q and k
#define KSPLIT 4
#define JITERS (NN / KSPLIT / 64)     // 16
#define KSTRIDE 272                   // 17 granules: padded K row (bank-spread)
#define DEFER_THR 8.0f                // defer-max: P bounded by 2^8=256 < fp8 max 448

// sigma(c): channel permutation applied to BOTH q8 and k8 columns so that a
// lane's (q4, kc) and (q4, kc+1) 8B fragments are 16B-contiguous ->
// QK LDS reads become ds_read_b128 (16 reads/wave-iter instead of 32) and
// the read pattern (bank group = (m + q4 + 4*c16) mod 8) is conflict-free.
// Dot products over c are invariant under a shared permutation; V untouched.
#define SIGMA(c) (((c) & 0xC0) | (((c) & 0x18) << 1) | (((c) & 0x20) >> 2) | ((c) & 7))

typedef __bf16 bf16x8 __attribute__((ext_vector_type(8)));
typedef float  f32x4  __attribute__((ext_vector_type(4)));

typedef __attribute__((address_space(1))) const void g_void;
typedef __attribute__((address_space(3))) void l_void;

__device__ __forceinline__ unsigned short f2bf(float f) {
  unsigned u = __builtin_bit_cast(unsigned, f);
  u += 0x7fffu + ((u >> 16) & 1u);
  return (unsigned short)(u >> 16);
}
__device__ __forceinline__ float bf2f(unsigned short s) {
  return __builtin_bit_cast(float, (unsigned)s << 16);
}

__device__ __forceinline__ f32x4 mfma16(bf16x8 a, bf16x8 b, f32x4 c) {
  return __builtin_amdgcn_mfma_f32_16x16x32_bf16(a, b, c, 0, 0, 0);
}
__device__ __forceinline__ f32x4 mfma8(long a, long b, f32x4 c) {
  return __builtin_amdgcn_mfma_f32_16x16x32_fp8_fp8(a, b, c, 0, 0, 0);
}

__device__ __forceinline__ bf16x8 ldfrag(const unsigned short* p) {
  return __builtin_bit_cast(bf16x8, *(const uint4*)p);
}

// ---- fused: weights fp32->bf16 (blocks 0..255) + GroupNorm stats (256..511) ----
__global__ __launch_bounds__(256) void pre(const float* __restrict__ wq,
    const float* __restrict__ wk, const float* __restrict__ wv,
    const float* __restrict__ wo, const float* __restrict__ x,
    unsigned short* __restrict__ wbf, float* __restrict__ part) {
  if (blockIdx.x < 256) {
    int mat = blockIdx.x >> 6, blk = blockIdx.x & 63;
    const float* s = mat == 0 ? wq : mat == 1 ? wk : mat == 2 ? wv : wo;
    int i = (blk * 256 + threadIdx.x) * 4;
    float4 v = *(const float4*)&s[i];
    unsigned short* d = wbf + (size_t)mat * CC * CC + i;
    d[0] = f2bf(v.x); d[1] = f2bf(v.y); d[2] = f2bf(v.z); d[3] = f2bf(v.w);
    return;
  }
  int bx = blockIdx.x - 256;
  int pair = bx >> 1, h = bx & 1;
  const float* xp = x + (size_t)pair * (CPG * NN) + (size_t)h * (CPG * NN / 2);
  float s = 0.f, s2 = 0.f;
  for (int i = threadIdx.x; i < CPG * NN / 8; i += 256) {
    float4 v = ((const float4*)xp)[i];
    s += v.x + v.y + v.z + v.w;
    s2 += v.x * v.x + v.y * v.y + v.z * v.z + v.w * v.w;
  }
  for (int o = 32; o; o >>= 1) { s += __shfl_down(s, o); s2 += __shfl_down(s2, o); }
  __shared__ float rs[4], rs2[4];
  int wid = threadIdx.x >> 6, lane = threadIdx.x & 63;
  if (lane == 0) { rs[wid] = s; rs2[wid] = s2; }
  __syncthreads();
  if (threadIdx.x == 0) {
    part[bx * 2 + 0] = rs[0] + rs[1] + rs[2] + rs[3];
    part[bx * 2 + 1] = rs2[0] + rs2[1] + rs2[2] + rs2[3];
  }
}

// ---- fused GroupNorm + QKV, all three projections per block ----
// grid 256 = 4 b x 64 ntiles (low3 XCD-pins), 512 threads (8 waves).
// q8/k8 columns are written at SIGMA(o); v8 rows at jp (see below).
__global__ __launch_bounds__(512) void gqkv(const float* __restrict__ x,
    const float* __restrict__ gw, const float* __restrict__ gb,
    const float* __restrict__ part, const unsigned short* __restrict__ wbf,
    const float* __restrict__ bq, const float* __restrict__ bk,
    const float* __restrict__ bv,
    unsigned char* __restrict__ q8, unsigned char* __restrict__ k8,
    unsigned char* __restrict__ v8) {
  const int low = blockIdx.x & 7;
  const int b = low & 3, shalf = low >> 2;
  const int u = blockIdx.x >> 3;        // 0..31
  const int sidx = (u >> 4) * 2 + shalf;
  const int nt = sidx * 16 + (u & 15);
  const int n0 = nt * 64;
  __shared__ unsigned short Xs[64][CC + 8];
  int tid = threadIdx.x;
  const float* xb = x + (size_t)b * CC * NN;
  {                                      // 512 items of (8c x 4n), one each
    int item = tid;
    int g = item >> 4, nc = item & 15;
    int pair = b * NGROUPS + g;
    float s = part[pair * 4 + 0] + part[pair * 4 + 2];
    float s2 = part[pair * 4 + 1] + part[pair * 4 + 3];
    float mean = s / (CPG * NN);
    float inv = rsqrtf(s2 / (CPG * NN) - mean * mean + EPSG);
    unsigned short row[4][8];
#pragma unroll
    for (int cc = 0; cc < 8; ++cc) {
      int c = g * 8 + cc;
      float wv = gw[c];
      float scv = inv * wv;
      float biv = gb[c] - mean * scv;
      float4 v = *(const float4*)&xb[(size_t)c * NN + n0 + nc * 4];
      row[0][cc] = f2bf(v.x * scv + biv);
      row[1][cc] = f2bf(v.y * scv + biv);
      row[2][cc] = f2bf(v.z * scv + biv);
      row[3][cc] = f2bf(v.w * scv + biv);
    }
#pragma unroll
    for (int r = 0; r < 4; ++r)
      *(uint4*)&Xs[nc * 4 + r][g * 8] = *(const uint4*)&row[r][0];
  }
  __syncthreads();
  int w = tid >> 6, lane = tid & 63;
  int m = lane & 15, q4 = lane >> 4;
  int mode = w >> 2, wsub = w & 3;       // waves 0-3: Q rows; waves 4-7: K rows
  {
    bf16x8 xa[8];
#pragma unroll
    for (int k = 0; k < 8; ++k)
      xa[k] = ldfrag(&Xs[wsub * 16 + m][k * 32 + q4 * 8]);
    const unsigned short* W = wbf + (size_t)mode * CC * CC;
    const float* bias = mode ? bk : bq;
    unsigned char* dst = mode ? k8 : q8;
    for (int ot = 0; ot < 16; ++ot) {
      f32x4 acc = {0.f, 0.f, 0.f, 0.f};
#pragma unroll
      for (int k = 0; k < 8; ++k) {
        bf16x8 bf = ldfrag(&W[(size_t)(ot * 16 + m) * CC + k * 32 + q4 * 8]);
        acc = mfma16(xa[k], bf, acc);
      }
      int o = ot * 16 + m;
      int so = SIGMA(o);                 // permuted column for q8/k8
      float bia = bias[o];
      unsigned pk01 = __builtin_amdgcn_cvt_pk_fp8_f32(
          (acc[0] + bia) * QKSCL, (acc[1] + bia) * QKSCL, 0u, false);
      unsigned pk23 = __builtin_amdgcn_cvt_pk_fp8_f32(
          (acc[2] + bia) * QKSCL, (acc[3] + bia) * QKSCL, 0u, false);
      size_t base = ((size_t)b * NN + n0 + wsub * 16 + q4 * 4) * CC + so;
      dst[base]          = (unsigned char)(pk01 & 0xff);
      dst[base + CC]     = (unsigned char)((pk01 >> 8) & 0xff);
      dst[base + 2 * CC] = (unsigned char)(pk23 & 0xff);
      dst[base + 3 * CC] = (unsigned char)((pk23 >> 8) & 0xff);
    }
  }
  // ---- V phase: 8 waves split 4 o-groups x 2 nt4-halves ----
  {
    const unsigned short* Wv = wbf + 2 * CC * CC;
    int nthalf = w >> 2;                 // 0: nt4 {0,1}; 1: nt4 {2,3}
    for (int ot = 0; ot < 4; ++ot) {
      int o0 = (w & 3) * 64 + ot * 16;
      bf16x8 af[8];
#pragma unroll
      for (int k = 0; k < 8; ++k)
        af[k] = ldfrag(&Wv[(size_t)(o0 + m) * CC + k * 32 + q4 * 8]);
#pragma unroll
      for (int hh = 0; hh < 2; ++hh) {
        int nt4 = nthalf * 2 + hh;
        f32x4 acc = {0.f, 0.f, 0.f, 0.f};
#pragma unroll
        for (int k = 0; k < 8; ++k) {
          bf16x8 bfr = ldfrag(&Xs[nt4 * 16 + m][k * 32 + q4 * 8]);
          acc = mfma16(af[k], bfr, acc);
        }
        // K-dim permutation within the 64-block, derived for the b128 PV
        // read (one granule = both p-fragments): swap bit-pairs [5:4]<->[3:2].
        int j = nt4 * 16 + m;
        int jp = ((j & 0x0C) << 2) | ((j & 0x30) >> 2) | (j & 3);
        int n = n0 + jp;
        int o = o0 + q4 * 4;
        unsigned pk01 = __builtin_amdgcn_cvt_pk_fp8_f32(acc[0] + bv[o], acc[1] + bv[o + 1], 0u, false);
        unsigned pk23 = __builtin_amdgcn_cvt_pk_fp8_f32(acc[2] + bv[o + 2], acc[3] + bv[o + 3], 0u, false);
        size_t base = ((size_t)b * CC + o) * NN + n;
        v8[base]          = (unsigned char)(pk01 & 0xff);
        v8[base + NN]     = (unsigned char)((pk01 >> 8) & 0xff);
        v8[base + 2 * NN] = (unsigned char)(pk23 & 0xff);
        v8[base + 3 * NN] = (unsigned char)((pk23 >> 8) & 0xff);
      }
    }
  }
}

// DMA one 64-j fp8 K tile into PADDED LDS (row stride 272B = 17 granules).
// Layout-agnostic byte copy (k8 rows are already sigma-permuted).
// 256-thread version: 1088 granules = 4x256 + 64-thread tail (wave 0).
__device__ __forceinline__ void stageK8(const unsigned char* __restrict__ kp,
    int j0, unsigned char* Kb, int tid) {
#pragma unroll
  for (int t = 0; t < 4; ++t) {
    int item = t * 256 + tid;
    int row = item / 17, g = item % 17;
    int gs = (g == 16) ? 0 : g;
    const unsigned char* gp = kp + (size_t)(j0 + row) * CC + gs * 16;
    __builtin_amdgcn_global_load_lds((g_void*)gp, (l_void*)(Kb + item * 16), 16, 0, 0);
  }
  if (tid < 64) {                       // wave-0-uniform tail: items 1024..1087
    int item = 1024 + tid;
    int row = item / 17, g = item % 17;
    int gs = (g == 16) ? 0 : g;
    const unsigned char* gp = kp + (size_t)(j0 + row) * CC + gs * 16;
    __builtin_amdgcn_global_load_lds((g_void*)gp, (l_void*)(Kb + item * 16), 16, 0, 0);
  }
}
// DMA one 64-j fp8 V tile (256 rows x 64B, VSTRIDE=64 -- round-8 staging
// coalescing preserved: 4 lanes per row read the row's 64B segment).
// Granule select gg = (gl - h(row)) & 3, h(r) = (r + (r>>2)) & 3: per-row
// permutation of the segment so the READ side (granule q4 at LDS granule
// (q4+h)&3) is one conflict-free ds_read_b128 per ct (2 lanes/bank-group
// per phase = the b128 floor).
__device__ __forceinline__ void stageV8(const unsigned char* __restrict__ vp,
    int j0, unsigned char* Vb, int tid) {
#pragma unroll
  for (int t = 0; t < 4; ++t) {
    int item = t * 256 + tid;
    int row = item >> 2, gl = item & 3;
    int h = (row + (row >> 2)) & 3;
    int gg = (gl - h) & 3;
    const unsigned char* g = vp + (size_t)row * NN + j0 + gg * 16;
    __builtin_amdgcn_global_load_lds((g_void*)g, (l_void*)(Vb + item * 16), 16, 0, 0);
  }
}

// ---- flash attention, S^T form: grid 512 = 16 (s,b) x 32 itiles, 256 thr ----
// 4 waves/block; each wave owns 32 Q-rows (subtiles A,B) sharing every
// K/V-fragment LDS read; sigma layout -> QK = 16 conflict-free ds_read_b128.
// V: jp re-derived so one b128 granule = both p-fragments -> PV = 16
// conflict-free ds_read_b128 (was 32 b64 at 4-way conflict = 4.1 kcyc/
// CU-iter). Staging identical to round 8 (VSTRIDE=64, 64B segments).
// CROSS-ITERATION PV PIPELINE: iteration jt issues one merged MFMA burst
// {QK(jt), PV(jt-1)}, then barrier B, stage(jt+1), softmax(jt)->pd(jt).
// K single buffer; V double buffer. LDS 17408 + 2*16384 = 50176B.
__global__ __launch_bounds__(256, 2) void attn(const unsigned char* __restrict__ q8,
    const unsigned char* __restrict__ k8, const unsigned char* __restrict__ v8,
    unsigned short* __restrict__ accP, float* __restrict__ mlP) {
  const int grp = blockIdx.x & 15;
  const int s = grp >> 2, b = grp & 3;
  const int it = blockIdx.x >> 4;       // 0..31
  const int i0 = it * 128;
  __shared__ __align__(16) unsigned char pool[50176];
  unsigned char* Kd  = pool;                    // 64*272 = 17408 B (single)
  unsigned char* Vd0 = pool + 17408;            // 16384 B
  unsigned char* Vd1 = pool + 33792;            // 16384 B
  int tid = threadIdx.x, w = tid >> 6, lane = tid & 63;
  int m = lane & 15, q4 = lane >> 4;
  const unsigned char* kp = k8 + (size_t)b * NN * CC;
  const unsigned char* vp = v8 + (size_t)b * CC * NN;
  const int iA0 = i0 + w * 32;          // subtile A rows; B = A + 16
  long qaA[8], qaB[8];
#pragma unroll
  for (int t = 0; t < 4; ++t) {         // sigma layout: 16B-contiguous kc pairs
    uint4 va = *(const uint4*)&q8[((size_t)b * NN + iA0 + m) * CC + t * 64 + q4 * 16];
    uint4 vb = *(const uint4*)&q8[((size_t)b * NN + iA0 + 16 + m) * CC + t * 64 + q4 * 16];
    uint2 alo = {va.x, va.y}, ahi = {va.z, va.w};
    uint2 blo = {vb.x, vb.y}, bhi = {vb.z, vb.w};
    qaA[2 * t]     = __builtin_bit_cast(long, alo);
    qaA[2 * t + 1] = __builtin_bit_cast(long, ahi);
    qaB[2 * t]     = __builtin_bit_cast(long, blo);
    qaB[2 * t + 1] = __builtin_bit_cast(long, bhi);
  }
  f32x4 accA[16], accB[16];
#pragma unroll
  for (int i = 0; i < 16; ++i) {
    accA[i] = (f32x4){0.f, 0.f, 0.f, 0.f};
    accB[i] = (f32x4){0.f, 0.f, 0.f, 0.f};
  }
  float mrowA = -1e30f, lrowA = 0.f, mrowB = -1e30f, lrowB = 0.f;
  const int jbase = s * (NN / KSPLIT);
  stageK8(kp, jbase, Kd, tid);
  stageV8(vp, jbase, Vd0, tid);
  const unsigned char* Kbase = Kd + m * KSTRIDE + q4 * 16;  // b128 reads: +imm
  const int hm = (m + (m >> 2)) & 3;    // V read granule spread
  const int vgsel = ((q4 + hm) & 3) * 16;
  unsigned pdA[4] = {0, 0, 0, 0}, pdB[4] = {0, 0, 0, 0};    // carried pd(jt-1)
  for (int jt = 0; jt < JITERS; ++jt) {
    __syncthreads();         // barrier A: stage(jt) landed (this wave's own
                             // vmcnt(0) drain + all waves' barrier)
    const unsigned char* Vprev = (jt & 1) ? Vd0 : Vd1;  // V(jt-1) buffer
    f32x4 svA[4], svB[4];
    __builtin_amdgcn_s_setprio(1);
    // ---- merged MFMA burst: QK(jt) + PV(jt-1), fully independent ----
#pragma unroll
    for (int jt4 = 0; jt4 < 4; ++jt4) {
      f32x4 aA = {0.f, 0.f, 0.f, 0.f};
      f32x4 aB = {0.f, 0.f, 0.f, 0.f};
#pragma unroll
      for (int c16 = 0; c16 < 4; ++c16) {
        uint4 kq = *(const uint4*)&Kbase[jt4 * 16 * KSTRIDE + c16 * 64];
        uint2 l2 = {kq.x, kq.y}, h2 = {kq.z, kq.w};
        long klo = __builtin_bit_cast(long, l2);
        long khi = __builtin_bit_cast(long, h2);
        aA = mfma8(klo, qaA[2 * c16], aA);
        aB = mfma8(klo, qaB[2 * c16], aB);
        aA = mfma8(khi, qaA[2 * c16 + 1], aA);
        aB = mfma8(khi, qaB[2 * c16 + 1], aB);
      }
      svA[jt4] = aA;
      svB[jt4] = aB;
    }
    if (jt > 0) {            // PV(jt-1): one b128 per ct covers p0+p1
      uint2 puA0 = {pdA[0], pdA[1]}, puA1 = {pdA[2], pdA[3]};
      uint2 puB0 = {pdB[0], pdB[1]}, puB1 = {pdB[2], pdB[3]};
      long pTA0 = __builtin_bit_cast(long, puA0);
      long pTA1 = __builtin_bit_cast(long, puA1);
      long pTB0 = __builtin_bit_cast(long, puB0);
      long pTB1 = __builtin_bit_cast(long, puB1);
#pragma unroll
      for (int ct = 0; ct < 16; ++ct) {
        uint4 vv = *(const uint4*)&Vprev[(ct * 16 + m) * 64 + vgsel];
        uint2 vlo = {vv.x, vv.y}, vhi = {vv.z, vv.w};
        long vf0 = __builtin_bit_cast(long, vlo);
        long vf1 = __builtin_bit_cast(long, vhi);
        accA[ct] = mfma8(vf0, pTA0, accA[ct]);
        accB[ct] = mfma8(vf0, pTB0, accB[ct]);
        accA[ct] = mfma8(vf1, pTA1, accA[ct]);
        accB[ct] = mfma8(vf1, pTB1, accB[ct]);
      }
    }
    __builtin_amdgcn_s_setprio(0);
    __syncthreads();         // barrier B: all waves done reading Kd & V(jt-1)
                             // (no vmem outstanding -> cheap drain)
    if (jt + 1 < JITERS) {   // restage K (single buf) + V[(jt+1)&1]
      stageK8(kp, jbase + (jt + 1) * 64, Kd, tid);
      stageV8(vp, jbase + (jt + 1) * 64, ((jt + 1) & 1) ? Vd1 : Vd0, tid);
    }
    // ---- softmax(jt) -> pd(jt); consumed next iteration ----
    float mxA = -1e30f, mxB = -1e30f;
#pragma unroll
    for (int jt4 = 0; jt4 < 4; ++jt4) {
      mxA = fmaxf(mxA, fmaxf(fmaxf(svA[jt4][0], svA[jt4][1]), fmaxf(svA[jt4][2], svA[jt4][3])));
      mxB = fmaxf(mxB, fmaxf(fmaxf(svB[jt4][0], svB[jt4][1]), fmaxf(svB[jt4][2], svB[jt4][3])));
    }
    mxA = fmaxf(mxA, __shfl_xor(mxA, 16));
    mxA = fmaxf(mxA, __shfl_xor(mxA, 32));
    mxB = fmaxf(mxB, __shfl_xor(mxB, 16));
    mxB = fmaxf(mxB, __shfl_xor(mxB, 32));
    if (__any(mxA - mrowA > DEFER_THR)) {   // rare: update m, rescale A
      float mnewA = fmaxf(mrowA, mxA);
      float alphaA = exp2f(mrowA - mnewA);
      mrowA = mnewA;
      lrowA *= alphaA;
#pragma unroll
      for (int ct = 0; ct < 16; ++ct) accA[ct] *= alphaA;
    }
    if (__any(mxB - mrowB > DEFER_THR)) {   // rare: update m, rescale B
      float mnewB = fmaxf(mrowB, mxB);
      float alphaB = exp2f(mrowB - mnewB);
      mrowB = mnewB;
      lrowB *= alphaB;
#pragma unroll
      for (int ct = 0; ct < 16; ++ct) accB[ct] *= alphaB;
    }
    float rsumA = 0.f, rsumB = 0.f;
#pragma unroll
    for (int jt4 = 0; jt4 < 4; ++jt4) {
      float e0 = exp2f(svA[jt4][0] - mrowA);
      float e1 = exp2f(svA[jt4][1] - mrowA);
      float e2 = exp2f(svA[jt4][2] - mrowA);
      float e3 = exp2f(svA[jt4][3] - mrowA);
      rsumA += (e0 + e1) + (e2 + e3);
      unsigned d = __builtin_amdgcn_cvt_pk_fp8_f32(e0, e1, 0u, false);
      pdA[jt4] = __builtin_amdgcn_cvt_pk_fp8_f32(e2, e3, d, true);
      float f0 = exp2f(svB[jt4][0] - mrowB);
      float f1 = exp2f(svB[jt4][1] - mrowB);
      float f2 = exp2f(svB[jt4][2] - mrowB);
      float f3 = exp2f(svB[jt4][3] - mrowB);
      rsumB += (f0 + f1) + (f2 + f3);
      unsigned e = __builtin_amdgcn_cvt_pk_fp8_f32(f0, f1, 0u, false);
      pdB[jt4] = __builtin_amdgcn_cvt_pk_fp8_f32(f2, f3, e, true);
    }
    rsumA += __shfl_xor(rsumA, 16);
    rsumA += __shfl_xor(rsumA, 32);
    rsumB += __shfl_xor(rsumB, 16);
    rsumB += __shfl_xor(rsumB, 32);
    lrowA += rsumA;
    lrowB += rsumB;
  }
  // ---- epilogue PV(JITERS-1): V(15) in buf[15&1]=Vd1, untouched since ----
  {
    const unsigned char* Vlast = ((JITERS - 1) & 1) ? Vd1 : Vd0;
    uint2 puA0 = {pdA[0], pdA[1]}, puA1 = {pdA[2], pdA[3]};
    uint2 puB0 = {pdB[0], pdB[1]}, puB1 = {pdB[2], pdB[3]};
    long pTA0 = __builtin_bit_cast(long, puA0);
    long pTA1 = __builtin_bit_cast(long, puA1);
    long pTB0 = __builtin_bit_cast(long, puB0);
    long pTB1 = __builtin_bit_cast(long, puB1);
#pragma unroll
    for (int ct = 0; ct < 16; ++ct) {
      uint4 vv = *(const uint4*)&Vlast[(ct * 16 + m) * 64 + vgsel];
      uint2 vlo = {vv.x, vv.y}, vhi = {vv.z, vv.w};
      long vf0 = __builtin_bit_cast(long, vlo);
      long vf1 = __builtin_bit_cast(long, vhi);
      accA[ct] = mfma8(vf0, pTA0, accA[ct]);
      accB[ct] = mfma8(vf0, pTB0, accB[ct]);
      accA[ct] = mfma8(vf1, pTA1, accA[ct]);
      accB[ct] = mfma8(vf1, pTB1, accB[ct]);
    }
  }
  // epilogue: per-lane (i = m) stats for both subtiles; O^T -> LDS transpose
  // -> coalesced store. 128 rows in two 64-row passes (waves 0-1, then 2-3).
  size_t rqA = (size_t)(s * BB + b) * NN + iA0 + m;
  if (q4 == 0) {
    mlP[rqA * 2 + 0] = mrowA;
    mlP[rqA * 2 + 1] = lrowA;
    mlP[(rqA + 16) * 2 + 0] = mrowB;
    mlP[(rqA + 16) * 2 + 1] = lrowB;
  }
  __syncthreads();                      // all PV reads done before pool reuse
  unsigned short* tp = (unsigned short*)pool;   // 64 rows x 260 shorts = 33.3KB
#pragma unroll
  for (int half = 0; half < 2; ++half) {
    if ((w >> 1) == half) {
      int rbase = (w & 1) * 32;
#pragma unroll
      for (int ct = 0; ct < 16; ++ct) {
        unsigned loA = f2bf(accA[ct][0]) | ((unsigned)f2bf(accA[ct][1]) << 16);
        unsigned hiA = f2bf(accA[ct][2]) | ((unsigned)f2bf(accA[ct][3]) << 16);
        uint2 pkA = {loA, hiA};
        *(uint2*)&tp[(rbase + m) * 260 + ct * 16 + q4 * 4] = pkA;
        unsigned loB = f2bf(accB[ct][0]) | ((unsigned)f2bf(accB[ct][1]) << 16);
        unsigned hiB = f2bf(accB[ct][2]) | ((unsigned)f2bf(accB[ct][3]) << 16);
        uint2 pkB = {loB, hiB};
        *(uint2*)&tp[(rbase + 16 + m) * 260 + ct * 16 + q4 * 4] = pkB;
      }
    }
    __syncthreads();
#pragma unroll
    for (int u = 0; u < 8; ++u) {
      int id = u * 256 + tid;           // 2048 items = 64 rows x 32 chunks
      int row = id >> 5, ck = id & 31;
      uint4 v = *(const uint4*)&tp[row * 260 + ck * 8];
      *(uint4*)&accP[((size_t)(s * BB + b) * NN + i0 + half * 64 + row) * CC + ck * 8] = v;
    }
    __syncthreads();
  }
}

// ---- output projection + combine partials + bias + residual; grid 512 ----
__global__ __launch_bounds__(256) void proj(const unsigned short* __restrict__ accP,
    const float* __restrict__ mlP, const unsigned short* __restrict__ Wo,
    const float* __restrict__ bo, const float* __restrict__ x,
    float* __restrict__ out) {
  const int b = blockIdx.x >> 7, nt = blockIdx.x & 127;
  const int n0 = nt * 32;
  __shared__ unsigned short As[32][CC + 8];
  __shared__ float wr[KSPLIT][36];
  int tid = threadIdx.x;
  if (tid < 32) {
    int n = n0 + tid;
    float mv[KSPLIT], lv[KSPLIT], M = -1e30f;
#pragma unroll
    for (int s = 0; s < KSPLIT; ++s) {
      size_t rq = (size_t)(s * BB + b) * NN + n;
      mv[s] = mlP[rq * 2];
      lv[s] = mlP[rq * 2 + 1];
      M = fmaxf(M, mv[s]);
    }
    float ws[KSPLIT], d = 0.f;
#pragma unroll
    for (int s = 0; s < KSPLIT; ++s) {
      ws[s] = exp2f(mv[s] - M);
      d += lv[s] * ws[s];
    }
    float inv = 1.f / d;
#pragma unroll
    for (int s = 0; s < KSPLIT; ++s) wr[s][tid] = ws[s] * inv;
  }
  __syncthreads();
#pragma unroll
  for (int i = 0; i < 4; ++i) {
    int id = tid + 256 * i;
    int r = id >> 5, ck = id & 31;
    int n = n0 + r;
    float f[8] = {0.f, 0.f, 0.f, 0.f, 0.f, 0.f, 0.f, 0.f};
#pragma unroll
    for (int s = 0; s < KSPLIT; ++s) {
      uint4 a = *(const uint4*)&accP[((size_t)(s * BB + b) * NN + n) * CC + ck * 8];
      const unsigned* p = (const unsigned*)&a;
      float wgt = wr[s][r];
#pragma unroll
      for (int k = 0; k < 4; ++k) {
        f[k * 2 + 0] += bf2f((unsigned short)(p[k] & 0xffff)) * wgt;
        f[k * 2 + 1] += bf2f((unsigned short)(p[k] >> 16)) * wgt;
      }
    }
    unsigned short ov[8];
#pragma unroll
    for (int k = 0; k < 8; ++k) ov[k] = f2bf(f[k]);
    *(uint4*)&As[r][ck * 8] = *(const uint4*)&ov[0];
  }
  __syncthreads();
  int w = tid >> 6, lane = tid & 63, m = lane & 15, q4 = lane >> 4;
  for (int ot = 0; ot < 4; ++ot) {
    int o0 = w * 64 + ot * 16;
    bf16x8 af[8];
#pragma unroll
    for (int k = 0; k < 8; ++k)
      af[k] = ldfrag(&Wo[(size_t)(o0 + m) * CC + k * 32 + q4 * 8]);
#pragma unroll
    for (int nt4 = 0; nt4 < 2; ++nt4) {
      f32x4 a = {0.f, 0.f, 0.f, 0.f};
#pragma unroll
      for (int k = 0; k < 8; ++k) {
        bf16x8 bf = ldfrag(&As[nt4 * 16 + m][k * 32 + q4 * 8]);
        a = mfma16(af[k], bf, a);
      }
      int n = n0 + nt4 * 16 + m;
#pragma unroll
      for (int r = 0; r < 4; ++r) {
        int o = o0 + q4 * 4 + r;
        size_t idx = ((size_t)b * CC + o) * NN + n;
        out[idx] = x[idx] + bo[o] + a[r];
      }
    }
  }
}

extern "C" void kernel_launch(void* const* d_in, const int* in_sizes, int n_in,
                              void* d_out, int out_size, void* d_ws, size_t ws_size,
                              hipStream_t stream) {
  const float* x  = (const float*)d_in[0];
  const float* gw = (const float*)d_in[1];
  const float* gb = (const float*)d_in[2];
  const float* wq = (const float*)d_in[3];
  const float* bq = (const float*)d_in[4];
  const float* wk = (const float*)d_in[5];
  const float* bk = (const float*)d_in[6];
  const float* wv = (const float*)d_in[7];
  const float* bv = (const float*)d_in[8];
  const float* wo = (const float*)d_in[9];
  const float* bo = (const float*)d_in[10];

  const size_t M4 = (size_t)BB * NN * CC;
  unsigned short* wbf = (unsigned short*)d_ws;          // 4*65536 bf16
  unsigned short* accPb = wbf + 4 * CC * CC;            // KSPLIT*M4 bf16
  float* mlP  = (float*)(accPb + (size_t)KSPLIT * M4);  // KSPLIT*BBNN*2 f32
  float* part = mlP + (size_t)KSPLIT * BBNN * 2;        // 512 f32
  unsigned char* q8 = (unsigned char*)(part + 512);
  unsigned char* k8 = q8 + M4;
  unsigned char* v8 = k8 + M4;

  pre<<<512, 256, 0, stream>>>(wq, wk, wv, wo, x, wbf, part);
  gqkv<<<256, 512, 0, stream>>>(x, gw, gb, part, wbf, bq, bk, bv, q8, k8, v8);
  attn<<<KSPLIT * BB * 32, 256, 0, stream>>>(q8, k8, v8, accPb, mlP);
  proj<<<512, 256, 0, stream>>>(accPb, mlP, wbf + 3 * CC * CC, bo, x, (float*)d_out);
}